// Round 12
// baseline (287.696 us; speedup 1.0000x reference)
//
#include <hip/hip_runtime.h>
#include <hip/hip_bf16.h>

// MultiStreamAttention: B=8 H=W=64 C=384, heads=8 d=48, r=4 -> Hc=Wc=16 Nc=256, topk=4
// Inputs f32 or bf16 (runtime-detected); compute bf16 MFMA / f32 accum; output per detected mode.

#define Bq 8
#define Hh 8
#define Dd 48
#define Cc 384
#define NC 256
#define MFINE 32768    // B*H*W
#define KDIM 384
#define SCALE 0.14433756729740643f  // 1/sqrt(48)

typedef __attribute__((ext_vector_type(8))) short short8;
typedef __attribute__((ext_vector_type(4))) short short4v;
typedef __attribute__((ext_vector_type(4))) float floatx4;

// plane strides (elements)
#define QKVW_PLANE 12582912    // B*h*Nc*16*d

// workspace byte offsets (shared between host + fused kernel)
#define WS_XBF   88342528
#define WS_XC     9437184
#define WS_WQKV 113508352
#define WS_WDWX 114393088
#define WS_BDWX 114400000
#define WS_WDW  114400768
#define WS_BDW  114407680
#define WS_WPW  114408448
#define WS_BPW  114703360

// ---- convert one 4-elem tuple (16B f32 load / 8B passthrough) ----
__device__ __forceinline__ void cvt_seg(const void* src, __hip_bfloat16* dst, int blk, int n4, int fl) {
    int i = blk * 256 + threadIdx.x;
    if (i >= n4) return;
    if (fl) {
        floatx4 v = ((const floatx4*)src)[i];
        short4v o;
        for (int t = 0; t < 4; t++) {
            __hip_bfloat16 hb = __float2bfloat16(v[t]);
            o[t] = *(short*)&hb;
        }
        ((short4v*)dst)[i] = o;
    } else {
        ((short4v*)dst)[i] = ((const short4v*)src)[i];
    }
}

// ---- 0+1. FUSED: dtype detect (per-block, no separate launch) + 8 converts + pool ----
// Flag derivation: sample first 1024 ushorts of x. f32 data -> low mantissa halves random,
// (u>>7)&0xFF >= 0xC1 with p~0.246 over 512 low halves => ~126 hits. bf16 data -> exponent
// field, >=0xC1 means |v|>=2^66 => ~0 hits. Threshold 32: error probability negligible.
// Block 0 persists the flag for k_gemm_pw (visible at next kernel boundary).
__global__ __launch_bounds__(256) void k_cvt_pool(
        const void* sx, const void* s1, const void* s2, const void* s3,
        const void* s4, const void* s5, const void* s6, const void* s7,
        char* ws, int* flag) {
    __shared__ int cnt_sh;
    if (threadIdx.x == 0) cnt_sh = 0;
    __syncthreads();
    {
        const ushort* xs = (const ushort*)sx;
        int c = 0;
        for (int t = 0; t < 4; t++) {
            int e = (xs[threadIdx.x * 4 + t] >> 7) & 0xFF;
            if (e >= 0xC1) c++;
        }
        atomicAdd(&cnt_sh, c);
    }
    __syncthreads();
    int fl = (cnt_sh > 32) ? 1 : 0;
    if (blockIdx.x == 0 && threadIdx.x == 0) *flag = fl;
    int blk = blockIdx.x;
    if (blk < 12288) { cvt_seg(sx, (__hip_bfloat16*)(ws + WS_XBF),  blk,          3145728, fl); return; }
    if (blk < 12720) { cvt_seg(s1, (__hip_bfloat16*)(ws + WS_WQKV), blk - 12288,  110592, fl); return; }
    if (blk < 12724) { cvt_seg(s2, (__hip_bfloat16*)(ws + WS_WDWX), blk - 12720,  864,    fl); return; }
    if (blk < 12725) { cvt_seg(s3, (__hip_bfloat16*)(ws + WS_BDWX), blk - 12724,  96,     fl); return; }
    if (blk < 12729) { cvt_seg(s4, (__hip_bfloat16*)(ws + WS_WDW),  blk - 12725,  864,    fl); return; }
    if (blk < 12730) { cvt_seg(s5, (__hip_bfloat16*)(ws + WS_BDW),  blk - 12729,  96,     fl); return; }
    if (blk < 12874) { cvt_seg(s6, (__hip_bfloat16*)(ws + WS_WPW),  blk - 12730,  36864,  fl); return; }
    if (blk < 12875) { cvt_seg(s7, (__hip_bfloat16*)(ws + WS_BPW),  blk - 12874,  96,     fl); return; }
    // pool: blocks [12875, 14923) -> xc bf16 (B*Nc, C), 2 channels/thread, raw-input read
    int pb = blk - 12875;            // b*256 + n
    if (threadIdx.x >= 192) return;
    int b = pb >> 8, n = pb & 255;
    int yc = n >> 4, xcc = n & 15;
    int c0 = threadIdx.x * 2;
    size_t pixbase = (((size_t)(b * 64 + yc * 4)) * 64 + xcc * 4) * Cc + c0;
    float s0 = 0.f, s1v = 0.f;
    if (fl) {
        const float* xf = (const float*)sx;
        for (int i = 0; i < 4; i++)
            for (int j = 0; j < 4; j++) {
                float2 u = *(const float2*)(xf + pixbase + ((size_t)i * 64 + j) * Cc);
                s0 += u.x; s1v += u.y;
            }
    } else {
        const ushort* xb = (const ushort*)sx;
        for (int i = 0; i < 4; i++)
            for (int j = 0; j < 4; j++) {
                uint u = *(const uint*)(xb + pixbase + ((size_t)i * 64 + j) * Cc);
                s0 += __uint_as_float(u << 16);
                s1v += __uint_as_float(u & 0xFFFF0000u);
            }
    }
    __hip_bfloat16 h0 = __float2bfloat16(s0 * 0.0625f), h1 = __float2bfloat16(s1v * 0.0625f);
    uint uo = (uint)*(ushort*)&h0 | ((uint)*(ushort*)&h1 << 16);
    *(uint*)((ushort*)(ws + WS_XC) + (size_t)pb * Cc + c0) = uo;
}

// ---- async global->LDS, 16B per lane, wave-uniform LDS base ----
__device__ __forceinline__ void gload_lds16(const ushort* g, short* l) {
    __builtin_amdgcn_global_load_lds(
        (const __attribute__((address_space(1))) unsigned int*)(g),
        (__attribute__((address_space(3))) unsigned int*)(l), 16, 0, 0);
}

// ---- 128x128 tiled GEMM core, BK=64, double-buffered, COUNTED vmcnt (never 0 mid-loop) ----
// +T5 setprio around the compute phase: pays when heterogeneous waves co-resident (merged
// kernel has attn VALU-blocks + fine MFMA-blocks sharing CUs).
__device__ __forceinline__ void gemm128_dbuf(const ushort* A, const ushort* B,
                                             int tile_m, int tile_n,
                                             short* As, short* Bs, floatx4 (&acc)[4][4]) {
    int lane = threadIdx.x & 63, wave = threadIdx.x >> 6;
    int m_off = (wave >> 1) * 64, n_off = (wave & 1) * 64;
    int row16 = lane & 15, quad = lane >> 4;
    int srow = lane >> 3;                     // 0..7 within an 8-row staging group
    int scol = (((lane & 7) ^ srow) * 8);     // XOR-swizzled source column (shorts)
    for (int i = 0; i < 4; i++)
        for (int j = 0; j < 4; j++)
            acc[i][j] = (floatx4){0.f, 0.f, 0.f, 0.f};
    int rsw = (row16 & 7) * 8;                // read-side XOR (shorts)
#define STG(buf, k0)                                                                          \
    for (int g = wave; g < 16; g += 4) {                                                      \
        gload_lds16(A + (size_t)(tile_m + g * 8 + srow) * KDIM + (k0) + scol, As + (buf) * 8192 + g * 512); \
        gload_lds16(B + (size_t)(tile_n + g * 8 + srow) * KDIM + (k0) + scol, Bs + (buf) * 8192 + g * 512); \
    }
    STG(0, 0)
    int cur = 0;
    for (int k0 = 0; k0 < KDIM; k0 += 64) {
        if (k0 + 64 < KDIM) {
            STG(cur ^ 1, k0 + 64)                           // prefetch next step's tiles
            asm volatile("s_waitcnt vmcnt(8)" ::: "memory"); // wait ONLY cur's 8 loads; 8 stay in flight
        } else {
            asm volatile("s_waitcnt vmcnt(0)" ::: "memory"); // tail: nothing more in flight behind cur
        }
        __builtin_amdgcn_s_barrier();
        __builtin_amdgcn_sched_barrier(0);                   // don't hoist ds_reads above the wait
        __builtin_amdgcn_s_setprio(1);
        const short* Ab = As + cur * 8192;
        const short* Bb = Bs + cur * 8192;
        for (int h = 0; h < 2; h++) {
            short8 af[4], bf[4];
            for (int mt = 0; mt < 4; mt++)
                af[mt] = *(const short8*)(Ab + (m_off + mt * 16 + row16) * 64 + (((h * 4 + quad) * 8) ^ rsw));
            for (int nt = 0; nt < 4; nt++)
                bf[nt] = *(const short8*)(Bb + (n_off + nt * 16 + row16) * 64 + (((h * 4 + quad) * 8) ^ rsw));
            for (int mt = 0; mt < 4; mt++)
                for (int nt = 0; nt < 4; nt++)
                    acc[mt][nt] = __builtin_amdgcn_mfma_f32_16x16x32_bf16(af[mt], bf[nt], acc[mt][nt], 0, 0, 0);
        }
        __builtin_amdgcn_s_setprio(0);
        __builtin_amdgcn_sched_barrier(0);                   // don't sink ds_reads past the barrier
        __builtin_amdgcn_s_barrier();                        // compute done before next STG overwrites cur
        cur ^= 1;
    }
#undef STG
}

// ---- single-buffered BK=64 variant (verified best for k_gemm_pw): 32 KB LDS, 4+ blocks/CU ----
__device__ __forceinline__ void gemm128_sb(const ushort* A, const ushort* B,
                                           int tile_m, int tile_n,
                                           short* As, short* Bs, floatx4 (&acc)[4][4]) {
    int lane = threadIdx.x & 63, wave = threadIdx.x >> 6;
    int m_off = (wave >> 1) * 64, n_off = (wave & 1) * 64;
    int row16 = lane & 15, quad = lane >> 4;
    int srow = lane >> 3;                     // 0..7 within an 8-row staging group
    int scol = (((lane & 7) ^ srow) * 8);     // XOR-swizzled source column (shorts)
    for (int i = 0; i < 4; i++)
        for (int j = 0; j < 4; j++)
            acc[i][j] = (floatx4){0.f, 0.f, 0.f, 0.f};
    int rsw = (row16 & 7) * 8;                // read-side XOR (shorts)
    for (int k0 = 0; k0 < KDIM; k0 += 64) {
        for (int g = wave; g < 16; g += 4) {
            gload_lds16(A + (size_t)(tile_m + g * 8 + srow) * KDIM + k0 + scol, As + g * 512);
            gload_lds16(B + (size_t)(tile_n + g * 8 + srow) * KDIM + k0 + scol, Bs + g * 512);
        }
        __syncthreads();
        for (int h = 0; h < 2; h++) {
            short8 af[4], bf[4];
            for (int mt = 0; mt < 4; mt++)
                af[mt] = *(const short8*)(As + (m_off + mt * 16 + row16) * 64 + (((h * 4 + quad) * 8) ^ rsw));
            for (int nt = 0; nt < 4; nt++)
                bf[nt] = *(const short8*)(Bs + (n_off + nt * 16 + row16) * 64 + (((h * 4 + quad) * 8) ^ rsw));
            for (int mt = 0; mt < 4; mt++)
                for (int nt = 0; nt < 4; nt++)
                    acc[mt][nt] = __builtin_amdgcn_mfma_f32_16x16x32_bf16(af[mt], bf[nt], acc[mt][nt], 0, 0, 0);
        }
        __syncthreads();
    }
}

// naive per-wave 16x16 tile (small coarse GEMM)
__device__ __forceinline__ floatx4 mfma_tile(const ushort* A, const ushort* W,
                                             int tile_m, int tile_n, int lane) {
    int row16 = lane & 15, quad = lane >> 4;
    const ushort* arow = A + (size_t)(tile_m + row16) * KDIM + quad * 8;
    const ushort* brow = W + (size_t)(tile_n + row16) * KDIM + quad * 8;
    floatx4 acc = {0.f, 0.f, 0.f, 0.f};
    for (int kk = 0; kk < KDIM; kk += 32) {
        short8 af = *(const short8*)(arow + kk);
        short8 bf = *(const short8*)(brow + kk);
        acc = __builtin_amdgcn_mfma_f32_16x16x32_bf16(af, bf, acc, 0, 0, 0);
    }
    return acc;
}

// ---- 2. coarse qkv gemm: (2048x384)@(1152x384)^T -> split-precision bf16 planes ----
__global__ __launch_bounds__(256) void k_gemm_qkv_coarse(const ushort* A, const ushort* W,
                                                         __hip_bfloat16* qh, __hip_bfloat16* ql,
                                                         __hip_bfloat16* kh, __hip_bfloat16* kl,
                                                         __hip_bfloat16* vt) {
    int lane = threadIdx.x & 63, wave = threadIdx.x >> 6;
    int tile_m = blockIdx.y * 32 + (wave >> 1) * 16;
    int tile_n = blockIdx.x * 32 + (wave & 1) * 16;
    floatx4 acc = mfma_tile(A, W, tile_m, tile_n, lane);
    int row16 = lane & 15, quad = lane >> 4;
    int n = tile_n + row16;
    int which = n / Cc, hd = n % Cc, head = hd / Dd, dim = hd % Dd;
    for (int rr = 0; rr < 4; rr++) {
        int m = tile_m + quad * 4 + rr;
        int b = m >> 8, nc = m & 255;
        float v = acc[rr];
        __hip_bfloat16 hi = __float2bfloat16(v);
        if (which == 0) {
            size_t p = ((size_t)((b * Hh + head) * NC + nc)) * Dd + dim;
            qh[p] = hi;
            ql[p] = __float2bfloat16(v - __bfloat162float(hi));
        } else if (which == 1) {
            size_t p = ((size_t)((b * Hh + head) * NC + nc)) * Dd + dim;
            kh[p] = hi;
            kl[p] = __float2bfloat16(v - __bfloat162float(hi));
        } else {
            vt[((size_t)((b * Hh + head) * Dd + dim)) * NC + nc] = hi;
        }
    }
}

// ---- 3+4 MERGED: coarse attention (blocks [0,256)) + fine qkv gemm (blocks [256,2560)) ----
#define PST 264   // shorts; row stride for P (16q x 256k), pad 8 keeps 16B align, 2-way banks
__global__ __launch_bounds__(256) void k_fine_cattn(
        const ushort* A, const ushort* W, __hip_bfloat16* qkvw,
        const ushort* qh, const ushort* ql, const ushort* kh, const ushort* kl,
        const ushort* vt, int* idx_out, __hip_bfloat16* xo) {
    __shared__ __align__(16) short smem[32768];  // fine: As dbuf|Bs dbuf (64KB); attn: Pl overlay (33.8KB)
    int lane = threadIdx.x & 63, wave = threadIdx.x >> 6;
    int row16 = lane & 15, quad = lane >> 4;
    if (blockIdx.x < 256) {
        // ---------------- coarse attention body (verified, unchanged) ----------------
        short* Pl = smem;                        // [4][16*PST] overlay
        int bh = blockIdx.x >> 2, qt = blockIdx.x & 3;
        int q0 = qt * 64 + wave * 16;
        short8 zf = {0, 0, 0, 0, 0, 0, 0, 0};
        const ushort* qhr = qh + ((size_t)(bh * NC + q0 + row16)) * Dd;
        const ushort* qlr = ql + ((size_t)(bh * NC + q0 + row16)) * Dd;
        short8 aqh0 = *(const short8*)(qhr + quad * 8);
        short8 aqh1 = (quad < 2) ? *(const short8*)(qhr + 32 + quad * 8) : zf;
        short8 aql0 = *(const short8*)(qlr + quad * 8);
        short8 aql1 = (quad < 2) ? *(const short8*)(qlr + 32 + quad * 8) : zf;
        floatx4 s[16];
        for (int nt = 0; nt < 16; nt++) {
            const ushort* khr = kh + ((size_t)(bh * NC + nt * 16 + row16)) * Dd;
            const ushort* klr = kl + ((size_t)(bh * NC + nt * 16 + row16)) * Dd;
            short8 bh0 = *(const short8*)(khr + quad * 8);
            short8 bh1 = (quad < 2) ? *(const short8*)(khr + 32 + quad * 8) : zf;
            short8 bl0 = *(const short8*)(klr + quad * 8);
            short8 bl1 = (quad < 2) ? *(const short8*)(klr + 32 + quad * 8) : zf;
            floatx4 a = {0.f, 0.f, 0.f, 0.f};
            a = __builtin_amdgcn_mfma_f32_16x16x32_bf16(aqh0, bh0, a, 0, 0, 0);
            a = __builtin_amdgcn_mfma_f32_16x16x32_bf16(aqh1, bh1, a, 0, 0, 0);
            a = __builtin_amdgcn_mfma_f32_16x16x32_bf16(aqh0, bl0, a, 0, 0, 0);
            a = __builtin_amdgcn_mfma_f32_16x16x32_bf16(aqh1, bl1, a, 0, 0, 0);
            a = __builtin_amdgcn_mfma_f32_16x16x32_bf16(aql0, bh0, a, 0, 0, 0);
            a = __builtin_amdgcn_mfma_f32_16x16x32_bf16(aql1, bh1, a, 0, 0, 0);
            s[nt] = a;
        }
        for (int rr = 0; rr < 4; rr++) {
            float sv[16];
            for (int nt = 0; nt < 16; nt++) sv[nt] = s[nt][rr] * SCALE;
            int chosen[4] = {-1, -1, -1, -1};
            float rowmax = 0.f;
            for (int it = 0; it < 4; it++) {
                float bv = -3.402823e38f; int bi = 0x7fffffff;
                for (int nt = 0; nt < 16; nt++) {
                    int ki = nt * 16 + row16;
                    bool skip = (ki == chosen[0]) | (ki == chosen[1]) | (ki == chosen[2]) | (ki == chosen[3]);
                    if (!skip && sv[nt] > bv) { bv = sv[nt]; bi = ki; }
                }
                for (int mk = 1; mk < 16; mk <<= 1) {
                    float ov = __shfl_xor(bv, mk); int oi = __shfl_xor(bi, mk);
                    if (ov > bv || (ov == bv && oi < bi)) { bv = ov; bi = oi; }
                }
                chosen[it] = bi;
                if (it == 0) rowmax = bv;
            }
            if (row16 == 0) {
                int q = q0 + quad * 4 + rr;
                for (int it = 0; it < 4; it++)
                    idx_out[((size_t)bh * NC + q) * 4 + it] = chosen[it];
            }
            float ex[16], sum = 0.f;
            for (int nt = 0; nt < 16; nt++) { ex[nt] = __expf(sv[nt] - rowmax); sum += ex[nt]; }
            for (int mk = 1; mk < 16; mk <<= 1) sum += __shfl_xor(sum, mk);
            float inv = 1.f / sum;
            for (int nt = 0; nt < 16; nt++) {
                __hip_bfloat16 hb = __float2bfloat16(ex[nt] * inv);
                Pl[(wave * 16 + quad * 4 + rr) * PST + nt * 16 + row16] = *(short*)&hb;
            }
        }
        const ushort* vbase = vt + (size_t)bh * Dd * NC;
        floatx4 o[3];
        for (int i = 0; i < 3; i++) o[i] = (floatx4){0.f, 0.f, 0.f, 0.f};
        for (int k0 = 0; k0 < 256; k0 += 32) {
            short8 pa = *(const short8*)&Pl[(wave * 16 + row16) * PST + k0 + quad * 8];
            for (int d2 = 0; d2 < 3; d2++) {
                short8 vb = *(const short8*)(vbase + (size_t)(d2 * 16 + row16) * NC + k0 + quad * 8);
                o[d2] = __builtin_amdgcn_mfma_f32_16x16x32_bf16(pa, vb, o[d2], 0, 0, 0);
            }
        }
        int b = bh >> 3, hh = bh & 7;
        for (int rr = 0; rr < 4; rr++) {
            int q = q0 + quad * 4 + rr;
            size_t base = ((size_t)(b * NC + q)) * Cc + hh * Dd;
            for (int d2 = 0; d2 < 3; d2++)
                xo[base + d2 * 16 + row16] = __float2bfloat16(o[d2][rr]);
        }
        return;
    }
    // ---------------- fine qkv gemm body (verified, unchanged; f offset by 256) ----------------
    floatx4 acc[4][4];
    int f = blockIdx.x - 256;
    int s = (f & 7) * 288 + (f >> 3);    // bijective: XCD x gets 32 consecutive row-tiles (all 9 col-tiles)
    int by = s / 9, bx = s - by * 9;
    int tile_m = by * 128, tile_n = bx * 128;
    gemm128_dbuf(A, W, tile_m, tile_n, smem, smem + 16384, acc);
    int m_off = (wave >> 1) * 64, n_off = (wave & 1) * 64;
    short* epi = smem + wave * 2304;     // private 32 rows x 72-short stride (144B, 16B-aligned rows)
    int r = lane >> 1, parity = lane & 1;
    for (int half = 0; half < 2; half++) {
        __syncthreads();
        for (int mt2 = 0; mt2 < 2; mt2++) {
            int mt = half * 2 + mt2;
            for (int nt = 0; nt < 4; nt++)
                for (int rr = 0; rr < 4; rr++) {
                    __hip_bfloat16 hb = __float2bfloat16(acc[mt][nt][rr]);
                    epi[(mt2 * 16 + quad * 4 + rr) * 72 + nt * 16 + row16] = *(short*)&hb;
                }
        }
        __syncthreads();
        int m = tile_m + m_off + half * 32 + r;
        int b = m >> 12, pix = m & 4095;
        int y = pix >> 6, x = pix & 63;
        int win = (y >> 2) * 16 + (x >> 2);
        int pos = (y & 3) * 4 + (x & 3);
        size_t mrow = ((size_t)b * Hh * NC * 16 * Dd) + ((size_t)win * 16 + pos) * Dd;
        for (int i = 0; i < 4; i++) {
            int j = parity + 2 * i;
            int n = tile_n + n_off + j * 8;
            int which = n / Cc, hd = n % Cc, head = hd / Dd, dim = hd % Dd;
            short8 val = *(const short8*)(epi + r * 72 + j * 8);
            size_t dst = (size_t)which * QKVW_PLANE + (size_t)head * (NC * 16 * Dd) + mrow + dim;
            *(short8*)((ushort*)qkvw + dst) = val;
        }
    }
}

// ---- 5. window attention (MFMA, one wave per window, no block barriers) ----
// XCD-grouped block swizzle (T1): 64 consecutive block-ids share one bh's 786KB K/V panel;
// swz keeps each panel's readers on one XCD L2 (4096 % 8 == 0 -> bijective).
#define PSTRIDE 80   // shorts; 160B row stride -> 16B-aligned b128 reads
#define VSTRIDE 72   // shorts; 144B row stride -> 16B-aligned, conflict-free b128 reads
__global__ __launch_bounds__(256) void k_win_attn(const __hip_bfloat16* qkvw, const int* idx, __hip_bfloat16* yo) {
    __shared__ __align__(16) short Pl[4][16 * PSTRIDE];   // P (16q x 64k) bf16, per wave
    __shared__ __align__(16) short Vt[4][48 * VSTRIDE];   // V^T (48d x 64k) bf16, per wave
    int lane = threadIdx.x & 63, wave = threadIdx.x >> 6;
    int blk = blockIdx.x;
    int swz = (blk & 7) * 512 + (blk >> 3);   // XCD-grouped, bijective
    int gw = swz * 4 + wave;             // global window id: bh*256 + n
    int bh = gw >> 8, n = gw & 255;
    int row16 = lane & 15, quad = lane >> 4;
    const ushort* qb  = (const ushort*)qkvw + (size_t)(bh * NC + n) * 768;
    const ushort* kwb = (const ushort*)qkvw + (size_t)QKVW_PLANE + (size_t)bh * NC * 768;
    const ushort* vwb = (const ushort*)qkvw + 2 * (size_t)QKVW_PLANE + (size_t)bh * NC * 768;
    int sel[4];
    for (int g = 0; g < 4; g++) sel[g] = idx[(size_t)gw * 4 + g];
    const ushort* vrow = vwb + (size_t)sel[quad] * 768 + row16 * 48;
    short8 vv[6];
    for (int i = 0; i < 6; i++) vv[i] = *(const short8*)(vrow + i * 8);
    short8 zf = {0, 0, 0, 0, 0, 0, 0, 0};
    short8 aq0 = *(const short8*)(qb + row16 * 48 + quad * 8);
    short8 aq1 = (quad < 2) ? *(const short8*)(qb + row16 * 48 + 32 + quad * 8) : zf;
    floatx4 s[4];
    for (int nt = 0; nt < 4; nt++) {
        const ushort* kb = kwb + (size_t)sel[nt] * 768 + row16 * 48;
        short8 bk0 = *(const short8*)(kb + quad * 8);
        short8 bk1 = (quad < 2) ? *(const short8*)(kb + 32 + quad * 8) : zf;
        floatx4 a = {0.f, 0.f, 0.f, 0.f};
        a = __builtin_amdgcn_mfma_f32_16x16x32_bf16(aq0, bk0, a, 0, 0, 0);
        a = __builtin_amdgcn_mfma_f32_16x16x32_bf16(aq1, bk1, a, 0, 0, 0);
        s[nt] = a;   // S[q=quad*4+rr][key=nt*16+row16]
    }
    for (int i = 0; i < 6; i++)
        for (int j = 0; j < 8; j++)
            Vt[wave][(i * 8 + j) * VSTRIDE + lane] = vv[i][j];
    for (int rr = 0; rr < 4; rr++) {
        float sv[4];
        float m = -3.402823e38f;
        for (int nt = 0; nt < 4; nt++) { sv[nt] = s[nt][rr] * SCALE; m = fmaxf(m, sv[nt]); }
        for (int msk = 1; msk < 16; msk <<= 1) m = fmaxf(m, __shfl_xor(m, msk));
        float sum = 0.f;
        for (int nt = 0; nt < 4; nt++) { sv[nt] = expf(sv[nt] - m); sum += sv[nt]; }
        for (int msk = 1; msk < 16; msk <<= 1) sum += __shfl_xor(sum, msk);
        float inv = 1.f / sum;
        for (int nt = 0; nt < 4; nt++) {
            __hip_bfloat16 hb = __float2bfloat16(sv[nt] * inv);
            Pl[wave][(quad * 4 + rr) * PSTRIDE + nt * 16 + row16] = *(short*)&hb;
        }
    }
    floatx4 o[3];
    for (int i = 0; i < 3; i++) o[i] = (floatx4){0.f, 0.f, 0.f, 0.f};
    for (int k0 = 0; k0 < 64; k0 += 32) {
        short8 pa = *(const short8*)&Pl[wave][row16 * PSTRIDE + k0 + quad * 8];
        for (int nt2 = 0; nt2 < 3; nt2++) {
            short8 vb = *(const short8*)&Vt[wave][(nt2 * 16 + row16) * VSTRIDE + k0 + quad * 8];
            o[nt2] = __builtin_amdgcn_mfma_f32_16x16x32_bf16(pa, vb, o[nt2], 0, 0, 0);
        }
    }
    int b = bh >> 3, hh = bh & 7;
    int wy = n >> 4, wx = n & 15;
    for (int rr = 0; rr < 4; rr++) {
        int q = quad * 4 + rr;
        int y = wy * 4 + (q >> 2), x = wx * 4 + (q & 3);
        size_t base = (((size_t)(b * 64 + y)) * 64 + x) * Cc + hh * Dd;
        for (int nt2 = 0; nt2 < 3; nt2++)
            yo[base + nt2 * 16 + row16] = __float2bfloat16(o[nt2][rr]);
    }
}

// ---- 6+7 FUSED: upsample(xo)->dwconv(dwx)->0.5 mix with yo -> [f32 regs] -> dwconv(dw) -> z ----
__global__ __launch_bounds__(192) void k_dwfuse(const __hip_bfloat16* xo, const __hip_bfloat16* yo,
                                                const __hip_bfloat16* dwx_w, const __hip_bfloat16* dwx_b,
                                                const __hip_bfloat16* dw_w, const __hip_bfloat16* dw_b,
                                                __hip_bfloat16* z) {
    int c0 = threadIdx.x * 2;
    int blk = blockIdx.x;                // (b*64+y)*8 + xchunk
    int xc = blk & 7, by = blk >> 3;
    int y = by & 63, b = by >> 6;
    int x0 = xc * 8;
    float wx0[9], wx1[9], wd0[9], wd1[9];
    for (int k = 0; k < 9; k++) {
        wx0[k] = __bfloat162float(dwx_w[c0 * 9 + k]);
        wx1[k] = __bfloat162float(dwx_w[(c0 + 1) * 9 + k]);
        wd0[k] = __bfloat162float(dw_w[c0 * 9 + k]);
        wd1[k] = __bfloat162float(dw_w[(c0 + 1) * 9 + k]);
    }
    float bx0 = __bfloat162float(dwx_b[c0]), bx1 = __bfloat162float(dwx_b[c0 + 1]);
    float bd0 = __bfloat162float(dw_b[c0]),  bd1 = __bfloat162float(dw_b[c0 + 1]);
    int r_base = (y >= 2 ? y - 2 : 0) >> 2;
    int c_base = x0 / 4 - 1;             // may be -1 for x0==0 (guarded loads)
    float px0[2][4], px1[2][4];
    for (int pr = 0; pr < 2; pr++) {
        int cr = r_base + pr;
        for (int pc = 0; pc < 4; pc++) {
            int cc2 = c_base + pc;
            uint u = (cr < 16 && cc2 >= 0 && cc2 < 16) ?
                *(const uint*)((const ushort*)xo + ((size_t)(b * NC + cr * 16 + cc2)) * Cc + c0) : 0u;
            px0[pr][pc] = __uint_as_float(u << 16);
            px1[pr][pc] = __uint_as_float(u & 0xFFFF0000u);
        }
    }
    float sr0[5][4], sr1[5][4];
#pragma unroll
    for (int f = 0; f < 5; f++) {
        int fy = y - 2 + f;
        bool valid = (fy >= 0 && fy < 64);
        int pr = valid ? ((fy >> 2) - r_base) : 0;   // 0 or 1
#pragma unroll
        for (int pc = 0; pc < 4; pc++) {
            float v0 = pr ? px0[1][pc] : px0[0][pc];
            float v1 = pr ? px1[1][pc] : px1[0][pc];
            sr0[f][pc] = valid ? v0 : 0.f;
            sr1[f][pc] = valid ? v1 : 0.f;
        }
    }
    float zp0[3][10], zp1[3][10];
#pragma unroll
    for (int r = 0; r < 3; r++)
#pragma unroll
        for (int cq = 0; cq < 10; cq++) { zp0[r][cq] = 0.f; zp1[r][cq] = 0.f; }
#pragma unroll
    for (int r = 0; r < 3; r++) {
        int fyz = y + r - 1;
        if (fyz < 0 || fyz > 63) continue;           // zpre row out of range -> stays 0
#pragma unroll
        for (int cq = 0; cq < 10; cq++) {
            int fxz = x0 - 1 + cq;
            if (fxz < 0 || fxz > 63) continue;       // zpre col out of range -> stays 0
            float a0 = bx0, a1 = bx1;
#pragma unroll
            for (int dy = -1; dy <= 1; dy++) {
#pragma unroll
                for (int dx = -1; dx <= 1; dx++) {
                    int t = cq - 1 + dx;             // compile-time
                    int pc = 1 + ((t + 8) / 4 - 2);  // floor division for t >= -2
                    int fx = fxz + dx;
                    bool cvalid = (fx >= 0 && fx < 64);
                    int f = r + dy + 1;              // compile-time row slice index 0..4
                    float t0 = cvalid ? sr0[f][pc] : 0.f;
                    float t1 = cvalid ? sr1[f][pc] : 0.f;
                    a0 += t0 * wx0[(dy + 1) * 3 + (dx + 1)];
                    a1 += t1 * wx1[(dy + 1) * 3 + (dx + 1)];
                }
            }
            uint uy = *(const uint*)((const ushort*)yo + (((size_t)(b * 64 + fyz)) * 64 + fxz) * Cc + c0);
            zp0[r][cq] = 0.5f * a0 + 0.5f * __uint_as_float(uy << 16);
            zp1[r][cq] = 0.5f * a1 + 0.5f * __uint_as_float(uy & 0xFFFF0000u);
        }
    }
    size_t obase = ((size_t)(b * 64 + y) * 64) * Cc + c0;
#pragma unroll
    for (int xq = 0; xq < 8; xq++) {
        float a0 = bd0, a1 = bd1;
#pragma unroll
        for (int dy = 0; dy < 3; dy++)
#pragma unroll
            for (int dx = 0; dx < 3; dx++) {
                a0 += zp0[dy][xq + dx] * wd0[dy * 3 + dx];
                a1 += zp1[dy][xq + dx] * wd1[dy * 3 + dx];
            }
        __hip_bfloat16 h0 = __float2bfloat16(a0), h1 = __float2bfloat16(a1);
        uint uo = (uint)*(ushort*)&h0 | ((uint)*(ushort*)&h1 << 16);
        *(uint*)((ushort*)z + obase + (size_t)(x0 + xq) * Cc) = uo;
    }
}

// ---- 8. pointwise gemm (tiled): (32768x384)@(384x384)^T + bias -> out (dtype per flag) ----
__global__ __launch_bounds__(256) void k_gemm_pw(const ushort* Z, const ushort* W, const __hip_bfloat16* bias,
                                                 void* out, const int* flag) {
    __shared__ __align__(16) short smem[16384];  // As[0:8192) | Bs[8192:16384); epilogue aliases
    floatx4 acc[4][4];
    int f = blockIdx.x;
    int s = (f & 7) * 96 + (f >> 3);     // bijective, 768 % 8 == 0
    int by = s / 3, bx = s - by * 3;
    int tile_m = by * 128, tile_n = bx * 128;
    gemm128_sb(Z, W, tile_m, tile_n, smem, smem + 8192, acc);
    int lane = threadIdx.x & 63, wave = threadIdx.x >> 6;
    int m_off = (wave >> 1) * 64, n_off = (wave & 1) * 64;
    int row16 = lane & 15, quad = lane >> 4;
    float* epi = (float*)smem + wave * 1216;   // private 16 rows x 76-float stride (304B, 16B-aligned rows)
    int f32out = *flag;
    int r4 = lane >> 2, c4 = lane & 3;
    for (int mt = 0; mt < 4; mt++) {
        __syncthreads();
        for (int nt = 0; nt < 4; nt++)
            for (int rr = 0; rr < 4; rr++)
                epi[(quad * 4 + rr) * 76 + nt * 16 + row16] = acc[mt][nt][rr];
        __syncthreads();
        int m = tile_m + m_off + mt * 16 + r4;
        for (int i = 0; i < 4; i++) {
            int j = c4 + 4 * i;
            int n0 = tile_n + n_off + j * 4;
            floatx4 v = *(const floatx4*)(epi + r4 * 76 + j * 4);
            short4v bb = *(const short4v*)((const ushort*)bias + n0);
            for (int t = 0; t < 4; t++) {
                short sb = bb[t];
                v[t] += __bfloat162float(*(const __hip_bfloat16*)&sb);
            }
            if (f32out) {
                *(floatx4*)((float*)out + (size_t)m * Cc + n0) = v;
            } else {
                short4v o;
                for (int t = 0; t < 4; t++) { __hip_bfloat16 hb = __float2bfloat16(v[t]); o[t] = *(short*)&hb; }
                *(short4v*)((__hip_bfloat16*)out + (size_t)m * Cc + n0) = o;
            }
        }
    }
}

extern "C" void kernel_launch(void* const* d_in, const int* in_sizes, int n_in,
                              void* d_out, int out_size, void* d_ws, size_t ws_size,
                              hipStream_t stream) {
    char* ws = (char*)d_ws;
    // coarse split-precision planes (each 786432 elems * 2B = 1,572,864 B)
    __hip_bfloat16* qhp  = (__hip_bfloat16*)(ws);
    __hip_bfloat16* qlp  = (__hip_bfloat16*)(ws + 1572864);
    __hip_bfloat16* khp  = (__hip_bfloat16*)(ws + 3145728);
    __hip_bfloat16* klp  = (__hip_bfloat16*)(ws + 4718592);
    __hip_bfloat16* vtp  = (__hip_bfloat16*)(ws + 6291456);    // ends 7,864,320
    __hip_bfloat16* xc   = (__hip_bfloat16*)(ws + WS_XC);      //  1,572,864 B
    int*            idx  = (int*)(ws + 11010048);              //    262,144 B
    __hip_bfloat16* xo   = (__hip_bfloat16*)(ws + 11272192);   //  1,572,864 B
    __hip_bfloat16* qkvw = (__hip_bfloat16*)(ws + 12845056);   // 75,497,472 B (3 bf16 planes)
    __hip_bfloat16* yo   = (__hip_bfloat16*)(ws + WS_XBF);     // 25,165,824 B
    __hip_bfloat16* xbf  = (__hip_bfloat16*)(ws + WS_XBF);     // aliases yo (x dead before win_attn)
    __hip_bfloat16* zbuf = (__hip_bfloat16*)(ws + 12845056);   // aliases qkvw (dead after win_attn);
                                                               // must NOT alias yo (k_dwfuse reads yo while writing z)
    __hip_bfloat16* wqkv = (__hip_bfloat16*)(ws + WS_WQKV);    //   884,736 B
    __hip_bfloat16* wdwx = (__hip_bfloat16*)(ws + WS_WDWX);
    __hip_bfloat16* bdwx = (__hip_bfloat16*)(ws + WS_BDWX);
    __hip_bfloat16* wdw  = (__hip_bfloat16*)(ws + WS_WDW);
    __hip_bfloat16* bdw  = (__hip_bfloat16*)(ws + WS_BDW);
    __hip_bfloat16* wpw  = (__hip_bfloat16*)(ws + WS_WPW);
    __hip_bfloat16* bpw  = (__hip_bfloat16*)(ws + WS_BPW);
    int*            flag = (int*)(ws + 114704128);

    // ONE fused launch: per-block dtype detect + 8 converts + pool (k_detect launch removed)
    k_cvt_pool<<<14923, 256, 0, stream>>>(d_in[0], d_in[1], d_in[2], d_in[3],
                                          d_in[4], d_in[5], d_in[6], d_in[7],
                                          ws, flag);

    k_gemm_qkv_coarse<<<dim3(36, 64), 256, 0, stream>>>((const ushort*)xc, (const ushort*)wqkv,
                                                        qhp, qlp, khp, klp, vtp);
    // MERGED: coarse attention (256 blocks, resident first) + fine qkv gemm (2304 blocks)
    k_fine_cattn<<<2560, 256, 0, stream>>>((const ushort*)xbf, (const ushort*)wqkv, qkvw,
                                           (const ushort*)qhp, (const ushort*)qlp,
                                           (const ushort*)khp, (const ushort*)klp,
                                           (const ushort*)vtp, idx, xo);
    k_win_attn<<<4096, 256, 0, stream>>>(qkvw, idx, yo);
    k_dwfuse<<<4096, 192, 0, stream>>>(xo, yo, wdwx, bdwx, wdw, bdw, zbuf);
    k_gemm_pw<<<768, 256, 0, stream>>>((const ushort*)zbuf, (const ushort*)wpw, bpw, d_out, flag);
}

// Round 13
// 279.082 us; speedup vs baseline: 1.0309x; 1.0309x over previous
//
#include <hip/hip_runtime.h>
#include <hip/hip_bf16.h>

// MultiStreamAttention: B=8 H=W=64 C=384, heads=8 d=48, r=4 -> Hc=Wc=16 Nc=256, topk=4
// Inputs f32 or bf16 (runtime-detected); compute bf16 MFMA / f32 accum; output per detected mode.

#define Bq 8
#define Hh 8
#define Dd 48
#define Cc 384
#define NC 256
#define MFINE 32768    // B*H*W
#define KDIM 384
#define SCALE 0.14433756729740643f  // 1/sqrt(48)

typedef __attribute__((ext_vector_type(8))) short short8;
typedef __attribute__((ext_vector_type(4))) short short4v;
typedef __attribute__((ext_vector_type(4))) float floatx4;

// plane strides (elements)
#define QKVW_PLANE 12582912    // B*h*Nc*16*d

// workspace byte offsets (shared between host + fused kernel)
#define WS_XBF   88342528
#define WS_XC     9437184
#define WS_WQKV 113508352
#define WS_WDWX 114393088
#define WS_BDWX 114400000
#define WS_WDW  114400768
#define WS_BDW  114407680
#define WS_WPW  114408448
#define WS_BPW  114703360

// ---- 0a. dtype detector: flag=1 if inputs are f32, 0 if bf16 ----
__global__ __launch_bounds__(256) void k_detect(const ushort* x, int* flag) {
    __shared__ int cnt;
    if (threadIdx.x == 0) cnt = 0;
    __syncthreads();
    int c = 0;
    for (int i = threadIdx.x; i < 8192; i += 256) {
        int e = (x[i] >> 7) & 0xFF;
        if (e >= 0xC1) c++;   // |v| >= 2^66: never for sane bf16 data, ~12% for f32-as-bf16
    }
    atomicAdd(&cnt, c);
    __syncthreads();
    if (threadIdx.x == 0) *flag = (cnt > 16) ? 1 : 0;
}

// ---- convert one 4-elem tuple (16B f32 load / 8B passthrough) ----
__device__ __forceinline__ void cvt_seg(const void* src, __hip_bfloat16* dst, int blk, int n4, int fl) {
    int i = blk * 256 + threadIdx.x;
    if (i >= n4) return;
    if (fl) {
        floatx4 v = ((const floatx4*)src)[i];
        short4v o;
        for (int t = 0; t < 4; t++) {
            __hip_bfloat16 hb = __float2bfloat16(v[t]);
            o[t] = *(short*)&hb;
        }
        ((short4v*)dst)[i] = o;
    } else {
        ((short4v*)dst)[i] = ((const short4v*)src)[i];
    }
}

// ---- 0b+1. FUSED: all 8 dtype-converts + pool in ONE launch ----
__global__ __launch_bounds__(256) void k_cvt_pool(
        const void* sx, const void* s1, const void* s2, const void* s3,
        const void* s4, const void* s5, const void* s6, const void* s7,
        char* ws, const int* flag) {
    int blk = blockIdx.x;
    int fl = *flag;
    if (blk < 12288) { cvt_seg(sx, (__hip_bfloat16*)(ws + WS_XBF),  blk,          3145728, fl); return; }
    if (blk < 12720) { cvt_seg(s1, (__hip_bfloat16*)(ws + WS_WQKV), blk - 12288,  110592, fl); return; }
    if (blk < 12724) { cvt_seg(s2, (__hip_bfloat16*)(ws + WS_WDWX), blk - 12720,  864,    fl); return; }
    if (blk < 12725) { cvt_seg(s3, (__hip_bfloat16*)(ws + WS_BDWX), blk - 12724,  96,     fl); return; }
    if (blk < 12729) { cvt_seg(s4, (__hip_bfloat16*)(ws + WS_WDW),  blk - 12725,  864,    fl); return; }
    if (blk < 12730) { cvt_seg(s5, (__hip_bfloat16*)(ws + WS_BDW),  blk - 12729,  96,     fl); return; }
    if (blk < 12874) { cvt_seg(s6, (__hip_bfloat16*)(ws + WS_WPW),  blk - 12730,  36864,  fl); return; }
    if (blk < 12875) { cvt_seg(s7, (__hip_bfloat16*)(ws + WS_BPW),  blk - 12874,  96,     fl); return; }
    // pool: blocks [12875, 14923) -> xc bf16 (B*Nc, C), 2 channels/thread, raw-input read
    int pb = blk - 12875;            // b*256 + n
    if (threadIdx.x >= 192) return;
    int b = pb >> 8, n = pb & 255;
    int yc = n >> 4, xcc = n & 15;
    int c0 = threadIdx.x * 2;
    size_t pixbase = (((size_t)(b * 64 + yc * 4)) * 64 + xcc * 4) * Cc + c0;
    float s0 = 0.f, s1v = 0.f;
    if (fl) {
        const float* xf = (const float*)sx;
        for (int i = 0; i < 4; i++)
            for (int j = 0; j < 4; j++) {
                float2 u = *(const float2*)(xf + pixbase + ((size_t)i * 64 + j) * Cc);
                s0 += u.x; s1v += u.y;
            }
    } else {
        const ushort* xb = (const ushort*)sx;
        for (int i = 0; i < 4; i++)
            for (int j = 0; j < 4; j++) {
                uint u = *(const uint*)(xb + pixbase + ((size_t)i * 64 + j) * Cc);
                s0 += __uint_as_float(u << 16);
                s1v += __uint_as_float(u & 0xFFFF0000u);
            }
    }
    __hip_bfloat16 h0 = __float2bfloat16(s0 * 0.0625f), h1 = __float2bfloat16(s1v * 0.0625f);
    uint uo = (uint)*(ushort*)&h0 | ((uint)*(ushort*)&h1 << 16);
    *(uint*)((ushort*)(ws + WS_XC) + (size_t)pb * Cc + c0) = uo;
}

// ---- async global->LDS, 16B per lane, wave-uniform LDS base ----
__device__ __forceinline__ void gload_lds16(const ushort* g, short* l) {
    __builtin_amdgcn_global_load_lds(
        (const __attribute__((address_space(1))) unsigned int*)(g),
        (__attribute__((address_space(3))) unsigned int*)(l), 16, 0, 0);
}

// ---- 128x128 tiled GEMM core, BK=64, double-buffered, COUNTED vmcnt (never 0 mid-loop) ----
// +T5 setprio around the compute phase (verified R12: merged kernel 68 -> 58 us).
__device__ __forceinline__ void gemm128_dbuf(const ushort* A, const ushort* B,
                                             int tile_m, int tile_n,
                                             short* As, short* Bs, floatx4 (&acc)[4][4]) {
    int lane = threadIdx.x & 63, wave = threadIdx.x >> 6;
    int m_off = (wave >> 1) * 64, n_off = (wave & 1) * 64;
    int row16 = lane & 15, quad = lane >> 4;
    int srow = lane >> 3;                     // 0..7 within an 8-row staging group
    int scol = (((lane & 7) ^ srow) * 8);     // XOR-swizzled source column (shorts)
    for (int i = 0; i < 4; i++)
        for (int j = 0; j < 4; j++)
            acc[i][j] = (floatx4){0.f, 0.f, 0.f, 0.f};
    int rsw = (row16 & 7) * 8;                // read-side XOR (shorts)
#define STG(buf, k0)                                                                          \
    for (int g = wave; g < 16; g += 4) {                                                      \
        gload_lds16(A + (size_t)(tile_m + g * 8 + srow) * KDIM + (k0) + scol, As + (buf) * 8192 + g * 512); \
        gload_lds16(B + (size_t)(tile_n + g * 8 + srow) * KDIM + (k0) + scol, Bs + (buf) * 8192 + g * 512); \
    }
    STG(0, 0)
    int cur = 0;
    for (int k0 = 0; k0 < KDIM; k0 += 64) {
        if (k0 + 64 < KDIM) {
            STG(cur ^ 1, k0 + 64)                           // prefetch next step's tiles
            asm volatile("s_waitcnt vmcnt(8)" ::: "memory"); // wait ONLY cur's 8 loads; 8 stay in flight
        } else {
            asm volatile("s_waitcnt vmcnt(0)" ::: "memory"); // tail: nothing more in flight behind cur
        }
        __builtin_amdgcn_s_barrier();
        __builtin_amdgcn_sched_barrier(0);                   // don't hoist ds_reads above the wait
        __builtin_amdgcn_s_setprio(1);
        const short* Ab = As + cur * 8192;
        const short* Bb = Bs + cur * 8192;
        for (int h = 0; h < 2; h++) {
            short8 af[4], bf[4];
            for (int mt = 0; mt < 4; mt++)
                af[mt] = *(const short8*)(Ab + (m_off + mt * 16 + row16) * 64 + (((h * 4 + quad) * 8) ^ rsw));
            for (int nt = 0; nt < 4; nt++)
                bf[nt] = *(const short8*)(Bb + (n_off + nt * 16 + row16) * 64 + (((h * 4 + quad) * 8) ^ rsw));
            for (int mt = 0; mt < 4; mt++)
                for (int nt = 0; nt < 4; nt++)
                    acc[mt][nt] = __builtin_amdgcn_mfma_f32_16x16x32_bf16(af[mt], bf[nt], acc[mt][nt], 0, 0, 0);
        }
        __builtin_amdgcn_s_setprio(0);
        __builtin_amdgcn_sched_barrier(0);                   // don't sink ds_reads past the barrier
        __builtin_amdgcn_s_barrier();                        // compute done before next STG overwrites cur
        cur ^= 1;
    }
#undef STG
}

// ---- single-buffered BK=64 variant (verified best for k_gemm_pw): 32 KB LDS, 4+ blocks/CU ----
__device__ __forceinline__ void gemm128_sb(const ushort* A, const ushort* B,
                                           int tile_m, int tile_n,
                                           short* As, short* Bs, floatx4 (&acc)[4][4]) {
    int lane = threadIdx.x & 63, wave = threadIdx.x >> 6;
    int m_off = (wave >> 1) * 64, n_off = (wave & 1) * 64;
    int row16 = lane & 15, quad = lane >> 4;
    int srow = lane >> 3;                     // 0..7 within an 8-row staging group
    int scol = (((lane & 7) ^ srow) * 8);     // XOR-swizzled source column (shorts)
    for (int i = 0; i < 4; i++)
        for (int j = 0; j < 4; j++)
            acc[i][j] = (floatx4){0.f, 0.f, 0.f, 0.f};
    int rsw = (row16 & 7) * 8;                // read-side XOR (shorts)
    for (int k0 = 0; k0 < KDIM; k0 += 64) {
        for (int g = wave; g < 16; g += 4) {
            gload_lds16(A + (size_t)(tile_m + g * 8 + srow) * KDIM + k0 + scol, As + g * 512);
            gload_lds16(B + (size_t)(tile_n + g * 8 + srow) * KDIM + k0 + scol, Bs + g * 512);
        }
        __syncthreads();
        for (int h = 0; h < 2; h++) {
            short8 af[4], bf[4];
            for (int mt = 0; mt < 4; mt++)
                af[mt] = *(const short8*)(As + (m_off + mt * 16 + row16) * 64 + (((h * 4 + quad) * 8) ^ rsw));
            for (int nt = 0; nt < 4; nt++)
                bf[nt] = *(const short8*)(Bs + (n_off + nt * 16 + row16) * 64 + (((h * 4 + quad) * 8) ^ rsw));
            for (int mt = 0; mt < 4; mt++)
                for (int nt = 0; nt < 4; nt++)
                    acc[mt][nt] = __builtin_amdgcn_mfma_f32_16x16x32_bf16(af[mt], bf[nt], acc[mt][nt], 0, 0, 0);
        }
        __syncthreads();
    }
}

// naive per-wave 16x16 tile (small coarse GEMM)
__device__ __forceinline__ floatx4 mfma_tile(const ushort* A, const ushort* W,
                                             int tile_m, int tile_n, int lane) {
    int row16 = lane & 15, quad = lane >> 4;
    const ushort* arow = A + (size_t)(tile_m + row16) * KDIM + quad * 8;
    const ushort* brow = W + (size_t)(tile_n + row16) * KDIM + quad * 8;
    floatx4 acc = {0.f, 0.f, 0.f, 0.f};
    for (int kk = 0; kk < KDIM; kk += 32) {
        short8 af = *(const short8*)(arow + kk);
        short8 bf = *(const short8*)(brow + kk);
        acc = __builtin_amdgcn_mfma_f32_16x16x32_bf16(af, bf, acc, 0, 0, 0);
    }
    return acc;
}

// ---- 2. coarse qkv gemm: (2048x384)@(1152x384)^T -> split-precision bf16 planes ----
__global__ __launch_bounds__(256) void k_gemm_qkv_coarse(const ushort* A, const ushort* W,
                                                         __hip_bfloat16* qh, __hip_bfloat16* ql,
                                                         __hip_bfloat16* kh, __hip_bfloat16* kl,
                                                         __hip_bfloat16* vt) {
    int lane = threadIdx.x & 63, wave = threadIdx.x >> 6;
    int tile_m = blockIdx.y * 32 + (wave >> 1) * 16;
    int tile_n = blockIdx.x * 32 + (wave & 1) * 16;
    floatx4 acc = mfma_tile(A, W, tile_m, tile_n, lane);
    int row16 = lane & 15, quad = lane >> 4;
    int n = tile_n + row16;
    int which = n / Cc, hd = n % Cc, head = hd / Dd, dim = hd % Dd;
    for (int rr = 0; rr < 4; rr++) {
        int m = tile_m + quad * 4 + rr;
        int b = m >> 8, nc = m & 255;
        float v = acc[rr];
        __hip_bfloat16 hi = __float2bfloat16(v);
        if (which == 0) {
            size_t p = ((size_t)((b * Hh + head) * NC + nc)) * Dd + dim;
            qh[p] = hi;
            ql[p] = __float2bfloat16(v - __bfloat162float(hi));
        } else if (which == 1) {
            size_t p = ((size_t)((b * Hh + head) * NC + nc)) * Dd + dim;
            kh[p] = hi;
            kl[p] = __float2bfloat16(v - __bfloat162float(hi));
        } else {
            vt[((size_t)((b * Hh + head) * Dd + dim)) * NC + nc] = hi;
        }
    }
}

// ---- 3+4 MERGED: coarse attention (blocks [0,256)) + fine qkv gemm (blocks [256,2560)) ----
#define PST 264   // shorts; row stride for P (16q x 256k), pad 8 keeps 16B align, 2-way banks
__global__ __launch_bounds__(256) void k_fine_cattn(
        const ushort* A, const ushort* W, __hip_bfloat16* qkvw,
        const ushort* qh, const ushort* ql, const ushort* kh, const ushort* kl,
        const ushort* vt, int* idx_out, __hip_bfloat16* xo) {
    __shared__ __align__(16) short smem[32768];  // fine: As dbuf|Bs dbuf (64KB); attn: Pl overlay (33.8KB)
    int lane = threadIdx.x & 63, wave = threadIdx.x >> 6;
    int row16 = lane & 15, quad = lane >> 4;
    if (blockIdx.x < 256) {
        // ---------------- coarse attention body (verified, unchanged) ----------------
        short* Pl = smem;                        // [4][16*PST] overlay
        int bh = blockIdx.x >> 2, qt = blockIdx.x & 3;
        int q0 = qt * 64 + wave * 16;
        short8 zf = {0, 0, 0, 0, 0, 0, 0, 0};
        const ushort* qhr = qh + ((size_t)(bh * NC + q0 + row16)) * Dd;
        const ushort* qlr = ql + ((size_t)(bh * NC + q0 + row16)) * Dd;
        short8 aqh0 = *(const short8*)(qhr + quad * 8);
        short8 aqh1 = (quad < 2) ? *(const short8*)(qhr + 32 + quad * 8) : zf;
        short8 aql0 = *(const short8*)(qlr + quad * 8);
        short8 aql1 = (quad < 2) ? *(const short8*)(qlr + 32 + quad * 8) : zf;
        floatx4 s[16];
        for (int nt = 0; nt < 16; nt++) {
            const ushort* khr = kh + ((size_t)(bh * NC + nt * 16 + row16)) * Dd;
            const ushort* klr = kl + ((size_t)(bh * NC + nt * 16 + row16)) * Dd;
            short8 bh0 = *(const short8*)(khr + quad * 8);
            short8 bh1 = (quad < 2) ? *(const short8*)(khr + 32 + quad * 8) : zf;
            short8 bl0 = *(const short8*)(klr + quad * 8);
            short8 bl1 = (quad < 2) ? *(const short8*)(klr + 32 + quad * 8) : zf;
            floatx4 a = {0.f, 0.f, 0.f, 0.f};
            a = __builtin_amdgcn_mfma_f32_16x16x32_bf16(aqh0, bh0, a, 0, 0, 0);
            a = __builtin_amdgcn_mfma_f32_16x16x32_bf16(aqh1, bh1, a, 0, 0, 0);
            a = __builtin_amdgcn_mfma_f32_16x16x32_bf16(aqh0, bl0, a, 0, 0, 0);
            a = __builtin_amdgcn_mfma_f32_16x16x32_bf16(aqh1, bl1, a, 0, 0, 0);
            a = __builtin_amdgcn_mfma_f32_16x16x32_bf16(aql0, bh0, a, 0, 0, 0);
            a = __builtin_amdgcn_mfma_f32_16x16x32_bf16(aql1, bh1, a, 0, 0, 0);
            s[nt] = a;
        }
        for (int rr = 0; rr < 4; rr++) {
            float sv[16];
            for (int nt = 0; nt < 16; nt++) sv[nt] = s[nt][rr] * SCALE;
            int chosen[4] = {-1, -1, -1, -1};
            float rowmax = 0.f;
            for (int it = 0; it < 4; it++) {
                float bv = -3.402823e38f; int bi = 0x7fffffff;
                for (int nt = 0; nt < 16; nt++) {
                    int ki = nt * 16 + row16;
                    bool skip = (ki == chosen[0]) | (ki == chosen[1]) | (ki == chosen[2]) | (ki == chosen[3]);
                    if (!skip && sv[nt] > bv) { bv = sv[nt]; bi = ki; }
                }
                for (int mk = 1; mk < 16; mk <<= 1) {
                    float ov = __shfl_xor(bv, mk); int oi = __shfl_xor(bi, mk);
                    if (ov > bv || (ov == bv && oi < bi)) { bv = ov; bi = oi; }
                }
                chosen[it] = bi;
                if (it == 0) rowmax = bv;
            }
            if (row16 == 0) {
                int q = q0 + quad * 4 + rr;
                for (int it = 0; it < 4; it++)
                    idx_out[((size_t)bh * NC + q) * 4 + it] = chosen[it];
            }
            float ex[16], sum = 0.f;
            for (int nt = 0; nt < 16; nt++) { ex[nt] = __expf(sv[nt] - rowmax); sum += ex[nt]; }
            for (int mk = 1; mk < 16; mk <<= 1) sum += __shfl_xor(sum, mk);
            float inv = 1.f / sum;
            for (int nt = 0; nt < 16; nt++) {
                __hip_bfloat16 hb = __float2bfloat16(ex[nt] * inv);
                Pl[(wave * 16 + quad * 4 + rr) * PST + nt * 16 + row16] = *(short*)&hb;
            }
        }
        const ushort* vbase = vt + (size_t)bh * Dd * NC;
        floatx4 o[3];
        for (int i = 0; i < 3; i++) o[i] = (floatx4){0.f, 0.f, 0.f, 0.f};
        for (int k0 = 0; k0 < 256; k0 += 32) {
            short8 pa = *(const short8*)&Pl[(wave * 16 + row16) * PST + k0 + quad * 8];
            for (int d2 = 0; d2 < 3; d2++) {
                short8 vb = *(const short8*)(vbase + (size_t)(d2 * 16 + row16) * NC + k0 + quad * 8);
                o[d2] = __builtin_amdgcn_mfma_f32_16x16x32_bf16(pa, vb, o[d2], 0, 0, 0);
            }
        }
        int b = bh >> 3, hh = bh & 7;
        for (int rr = 0; rr < 4; rr++) {
            int q = q0 + quad * 4 + rr;
            size_t base = ((size_t)(b * NC + q)) * Cc + hh * Dd;
            for (int d2 = 0; d2 < 3; d2++)
                xo[base + d2 * 16 + row16] = __float2bfloat16(o[d2][rr]);
        }
        return;
    }
    // ---------------- fine qkv gemm body (verified, unchanged; f offset by 256) ----------------
    floatx4 acc[4][4];
    int f = blockIdx.x - 256;
    int s = (f & 7) * 288 + (f >> 3);    // bijective: XCD x gets 32 consecutive row-tiles (all 9 col-tiles)
    int by = s / 9, bx = s - by * 9;
    int tile_m = by * 128, tile_n = bx * 128;
    gemm128_dbuf(A, W, tile_m, tile_n, smem, smem + 16384, acc);
    int m_off = (wave >> 1) * 64, n_off = (wave & 1) * 64;
    short* epi = smem + wave * 2304;     // private 32 rows x 72-short stride (144B, 16B-aligned rows)
    int r = lane >> 1, parity = lane & 1;
    for (int half = 0; half < 2; half++) {
        __syncthreads();
        for (int mt2 = 0; mt2 < 2; mt2++) {
            int mt = half * 2 + mt2;
            for (int nt = 0; nt < 4; nt++)
                for (int rr = 0; rr < 4; rr++) {
                    __hip_bfloat16 hb = __float2bfloat16(acc[mt][nt][rr]);
                    epi[(mt2 * 16 + quad * 4 + rr) * 72 + nt * 16 + row16] = *(short*)&hb;
                }
        }
        __syncthreads();
        int m = tile_m + m_off + half * 32 + r;
        int b = m >> 12, pix = m & 4095;
        int y = pix >> 6, x = pix & 63;
        int win = (y >> 2) * 16 + (x >> 2);
        int pos = (y & 3) * 4 + (x & 3);
        size_t mrow = ((size_t)b * Hh * NC * 16 * Dd) + ((size_t)win * 16 + pos) * Dd;
        for (int i = 0; i < 4; i++) {
            int j = parity + 2 * i;
            int n = tile_n + n_off + j * 8;
            int which = n / Cc, hd = n % Cc, head = hd / Dd, dim = hd % Dd;
            short8 val = *(const short8*)(epi + r * 72 + j * 8);
            size_t dst = (size_t)which * QKVW_PLANE + (size_t)head * (NC * 16 * Dd) + mrow + dim;
            *(short8*)((ushort*)qkvw + dst) = val;
        }
    }
}

// ---- 5. window attention (MFMA, one wave per window, no block barriers) ----
#define PSTRIDE 80   // shorts; 160B row stride -> 16B-aligned b128 reads
#define VSTRIDE 72   // shorts; 144B row stride -> 16B-aligned, conflict-free b128 reads
__global__ __launch_bounds__(256) void k_win_attn(const __hip_bfloat16* qkvw, const int* idx, __hip_bfloat16* yo) {
    __shared__ __align__(16) short Pl[4][16 * PSTRIDE];   // P (16q x 64k) bf16, per wave
    __shared__ __align__(16) short Vt[4][48 * VSTRIDE];   // V^T (48d x 64k) bf16, per wave
    int lane = threadIdx.x & 63, wave = threadIdx.x >> 6;
    int gw = blockIdx.x * 4 + wave;      // global window id: bh*256 + n
    int bh = gw >> 8, n = gw & 255;
    int row16 = lane & 15, quad = lane >> 4;
    const ushort* qb  = (const ushort*)qkvw + (size_t)(bh * NC + n) * 768;
    const ushort* kwb = (const ushort*)qkvw + (size_t)QKVW_PLANE + (size_t)bh * NC * 768;
    const ushort* vwb = (const ushort*)qkvw + 2 * (size_t)QKVW_PLANE + (size_t)bh * NC * 768;
    int sel[4];
    for (int g = 0; g < 4; g++) sel[g] = idx[(size_t)gw * 4 + g];
    const ushort* vrow = vwb + (size_t)sel[quad] * 768 + row16 * 48;
    short8 vv[6];
    for (int i = 0; i < 6; i++) vv[i] = *(const short8*)(vrow + i * 8);
    short8 zf = {0, 0, 0, 0, 0, 0, 0, 0};
    short8 aq0 = *(const short8*)(qb + row16 * 48 + quad * 8);
    short8 aq1 = (quad < 2) ? *(const short8*)(qb + row16 * 48 + 32 + quad * 8) : zf;
    floatx4 s[4];
    for (int nt = 0; nt < 4; nt++) {
        const ushort* kb = kwb + (size_t)sel[nt] * 768 + row16 * 48;
        short8 bk0 = *(const short8*)(kb + quad * 8);
        short8 bk1 = (quad < 2) ? *(const short8*)(kb + 32 + quad * 8) : zf;
        floatx4 a = {0.f, 0.f, 0.f, 0.f};
        a = __builtin_amdgcn_mfma_f32_16x16x32_bf16(aq0, bk0, a, 0, 0, 0);
        a = __builtin_amdgcn_mfma_f32_16x16x32_bf16(aq1, bk1, a, 0, 0, 0);
        s[nt] = a;   // S[q=quad*4+rr][key=nt*16+row16]
    }
    for (int i = 0; i < 6; i++)
        for (int j = 0; j < 8; j++)
            Vt[wave][(i * 8 + j) * VSTRIDE + lane] = vv[i][j];
    for (int rr = 0; rr < 4; rr++) {
        float sv[4];
        float m = -3.402823e38f;
        for (int nt = 0; nt < 4; nt++) { sv[nt] = s[nt][rr] * SCALE; m = fmaxf(m, sv[nt]); }
        for (int msk = 1; msk < 16; msk <<= 1) m = fmaxf(m, __shfl_xor(m, msk));
        float sum = 0.f;
        for (int nt = 0; nt < 4; nt++) { sv[nt] = expf(sv[nt] - m); sum += sv[nt]; }
        for (int msk = 1; msk < 16; msk <<= 1) sum += __shfl_xor(sum, msk);
        float inv = 1.f / sum;
        for (int nt = 0; nt < 4; nt++) {
            __hip_bfloat16 hb = __float2bfloat16(sv[nt] * inv);
            Pl[wave][(quad * 4 + rr) * PSTRIDE + nt * 16 + row16] = *(short*)&hb;
        }
    }
    floatx4 o[3];
    for (int i = 0; i < 3; i++) o[i] = (floatx4){0.f, 0.f, 0.f, 0.f};
    for (int k0 = 0; k0 < 64; k0 += 32) {
        short8 pa = *(const short8*)&Pl[wave][row16 * PSTRIDE + k0 + quad * 8];
        for (int nt2 = 0; nt2 < 3; nt2++) {
            short8 vb = *(const short8*)&Vt[wave][(nt2 * 16 + row16) * VSTRIDE + k0 + quad * 8];
            o[nt2] = __builtin_amdgcn_mfma_f32_16x16x32_bf16(pa, vb, o[nt2], 0, 0, 0);
        }
    }
    int b = bh >> 3, hh = bh & 7;
    int wy = n >> 4, wx = n & 15;
    for (int rr = 0; rr < 4; rr++) {
        int q = quad * 4 + rr;
        int y = wy * 4 + (q >> 2), x = wx * 4 + (q & 3);
        size_t base = (((size_t)(b * 64 + y)) * 64 + x) * Cc + hh * Dd;
        for (int nt2 = 0; nt2 < 3; nt2++)
            yo[base + nt2 * 16 + row16] = __float2bfloat16(o[nt2][rr]);
    }
}

// ---- 6+7 FUSED: upsample(xo)->dwconv(dwx)->0.5 mix with yo -> [f32 regs] -> dwconv(dw) -> z ----
__global__ __launch_bounds__(192) void k_dwfuse(const __hip_bfloat16* xo, const __hip_bfloat16* yo,
                                                const __hip_bfloat16* dwx_w, const __hip_bfloat16* dwx_b,
                                                const __hip_bfloat16* dw_w, const __hip_bfloat16* dw_b,
                                                __hip_bfloat16* z) {
    int c0 = threadIdx.x * 2;
    int blk = blockIdx.x;                // (b*64+y)*8 + xchunk
    int xc = blk & 7, by = blk >> 3;
    int y = by & 63, b = by >> 6;
    int x0 = xc * 8;
    float wx0[9], wx1[9], wd0[9], wd1[9];
    for (int k = 0; k < 9; k++) {
        wx0[k] = __bfloat162float(dwx_w[c0 * 9 + k]);
        wx1[k] = __bfloat162float(dwx_w[(c0 + 1) * 9 + k]);
        wd0[k] = __bfloat162float(dw_w[c0 * 9 + k]);
        wd1[k] = __bfloat162float(dw_w[(c0 + 1) * 9 + k]);
    }
    float bx0 = __bfloat162float(dwx_b[c0]), bx1 = __bfloat162float(dwx_b[c0 + 1]);
    float bd0 = __bfloat162float(dw_b[c0]),  bd1 = __bfloat162float(dw_b[c0 + 1]);
    int r_base = (y >= 2 ? y - 2 : 0) >> 2;
    int c_base = x0 / 4 - 1;             // may be -1 for x0==0 (guarded loads)
    float px0[2][4], px1[2][4];
    for (int pr = 0; pr < 2; pr++) {
        int cr = r_base + pr;
        for (int pc = 0; pc < 4; pc++) {
            int cc2 = c_base + pc;
            uint u = (cr < 16 && cc2 >= 0 && cc2 < 16) ?
                *(const uint*)((const ushort*)xo + ((size_t)(b * NC + cr * 16 + cc2)) * Cc + c0) : 0u;
            px0[pr][pc] = __uint_as_float(u << 16);
            px1[pr][pc] = __uint_as_float(u & 0xFFFF0000u);
        }
    }
    float sr0[5][4], sr1[5][4];
#pragma unroll
    for (int f = 0; f < 5; f++) {
        int fy = y - 2 + f;
        bool valid = (fy >= 0 && fy < 64);
        int pr = valid ? ((fy >> 2) - r_base) : 0;   // 0 or 1
#pragma unroll
        for (int pc = 0; pc < 4; pc++) {
            float v0 = pr ? px0[1][pc] : px0[0][pc];
            float v1 = pr ? px1[1][pc] : px1[0][pc];
            sr0[f][pc] = valid ? v0 : 0.f;
            sr1[f][pc] = valid ? v1 : 0.f;
        }
    }
    float zp0[3][10], zp1[3][10];
#pragma unroll
    for (int r = 0; r < 3; r++)
#pragma unroll
        for (int cq = 0; cq < 10; cq++) { zp0[r][cq] = 0.f; zp1[r][cq] = 0.f; }
#pragma unroll
    for (int r = 0; r < 3; r++) {
        int fyz = y + r - 1;
        if (fyz < 0 || fyz > 63) continue;           // zpre row out of range -> stays 0
#pragma unroll
        for (int cq = 0; cq < 10; cq++) {
            int fxz = x0 - 1 + cq;
            if (fxz < 0 || fxz > 63) continue;       // zpre col out of range -> stays 0
            float a0 = bx0, a1 = bx1;
#pragma unroll
            for (int dy = -1; dy <= 1; dy++) {
#pragma unroll
                for (int dx = -1; dx <= 1; dx++) {
                    int t = cq - 1 + dx;             // compile-time
                    int pc = 1 + ((t + 8) / 4 - 2);  // floor division for t >= -2
                    int fx = fxz + dx;
                    bool cvalid = (fx >= 0 && fx < 64);
                    int f = r + dy + 1;              // compile-time row slice index 0..4
                    float t0 = cvalid ? sr0[f][pc] : 0.f;
                    float t1 = cvalid ? sr1[f][pc] : 0.f;
                    a0 += t0 * wx0[(dy + 1) * 3 + (dx + 1)];
                    a1 += t1 * wx1[(dy + 1) * 3 + (dx + 1)];
                }
            }
            uint uy = *(const uint*)((const ushort*)yo + (((size_t)(b * 64 + fyz)) * 64 + fxz) * Cc + c0);
            zp0[r][cq] = 0.5f * a0 + 0.5f * __uint_as_float(uy << 16);
            zp1[r][cq] = 0.5f * a1 + 0.5f * __uint_as_float(uy & 0xFFFF0000u);
        }
    }
    size_t obase = ((size_t)(b * 64 + y) * 64) * Cc + c0;
#pragma unroll
    for (int xq = 0; xq < 8; xq++) {
        float a0 = bd0, a1 = bd1;
#pragma unroll
        for (int dy = 0; dy < 3; dy++)
#pragma unroll
            for (int dx = 0; dx < 3; dx++) {
                a0 += zp0[dy][xq + dx] * wd0[dy * 3 + dx];
                a1 += zp1[dy][xq + dx] * wd1[dy * 3 + dx];
            }
        __hip_bfloat16 h0 = __float2bfloat16(a0), h1 = __float2bfloat16(a1);
        uint uo = (uint)*(ushort*)&h0 | ((uint)*(ushort*)&h1 << 16);
        *(uint*)((ushort*)z + obase + (size_t)(x0 + xq) * Cc) = uo;
    }
}

// ---- 8. pointwise gemm (tiled): (32768x384)@(384x384)^T + bias -> out (dtype per flag) ----
__global__ __launch_bounds__(256) void k_gemm_pw(const ushort* Z, const ushort* W, const __hip_bfloat16* bias,
                                                 void* out, const int* flag) {
    __shared__ __align__(16) short smem[16384];  // As[0:8192) | Bs[8192:16384); epilogue aliases
    floatx4 acc[4][4];
    int f = blockIdx.x;
    int s = (f & 7) * 96 + (f >> 3);     // bijective, 768 % 8 == 0
    int by = s / 3, bx = s - by * 3;
    int tile_m = by * 128, tile_n = bx * 128;
    gemm128_sb(Z, W, tile_m, tile_n, smem, smem + 8192, acc);
    int lane = threadIdx.x & 63, wave = threadIdx.x >> 6;
    int m_off = (wave >> 1) * 64, n_off = (wave & 1) * 64;
    int row16 = lane & 15, quad = lane >> 4;
    float* epi = (float*)smem + wave * 1216;   // private 16 rows x 76-float stride (304B, 16B-aligned rows)
    int f32out = *flag;
    int r4 = lane >> 2, c4 = lane & 3;
    for (int mt = 0; mt < 4; mt++) {
        __syncthreads();
        for (int nt = 0; nt < 4; nt++)
            for (int rr = 0; rr < 4; rr++)
                epi[(quad * 4 + rr) * 76 + nt * 16 + row16] = acc[mt][nt][rr];
        __syncthreads();
        int m = tile_m + m_off + mt * 16 + r4;
        for (int i = 0; i < 4; i++) {
            int j = c4 + 4 * i;
            int n0 = tile_n + n_off + j * 4;
            floatx4 v = *(const floatx4*)(epi + r4 * 76 + j * 4);
            short4v bb = *(const short4v*)((const ushort*)bias + n0);
            for (int t = 0; t < 4; t++) {
                short sb = bb[t];
                v[t] += __bfloat162float(*(const __hip_bfloat16*)&sb);
            }
            if (f32out) {
                *(floatx4*)((float*)out + (size_t)m * Cc + n0) = v;
            } else {
                short4v o;
                for (int t = 0; t < 4; t++) { __hip_bfloat16 hb = __float2bfloat16(v[t]); o[t] = *(short*)&hb; }
                *(short4v*)((__hip_bfloat16*)out + (size_t)m * Cc + n0) = o;
            }
        }
    }
}

extern "C" void kernel_launch(void* const* d_in, const int* in_sizes, int n_in,
                              void* d_out, int out_size, void* d_ws, size_t ws_size,
                              hipStream_t stream) {
    char* ws = (char*)d_ws;
    // coarse split-precision planes (each 786432 elems * 2B = 1,572,864 B)
    __hip_bfloat16* qhp  = (__hip_bfloat16*)(ws);
    __hip_bfloat16* qlp  = (__hip_bfloat16*)(ws + 1572864);
    __hip_bfloat16* khp  = (__hip_bfloat16*)(ws + 3145728);
    __hip_bfloat16* klp  = (__hip_bfloat16*)(ws + 4718592);
    __hip_bfloat16* vtp  = (__hip_bfloat16*)(ws + 6291456);    // ends 7,864,320
    __hip_bfloat16* xc   = (__hip_bfloat16*)(ws + WS_XC);      //  1,572,864 B
    int*            idx  = (int*)(ws + 11010048);              //    262,144 B
    __hip_bfloat16* xo   = (__hip_bfloat16*)(ws + 11272192);   //  1,572,864 B
    __hip_bfloat16* qkvw = (__hip_bfloat16*)(ws + 12845056);   // 75,497,472 B (3 bf16 planes)
    __hip_bfloat16* yo   = (__hip_bfloat16*)(ws + WS_XBF);     // 25,165,824 B
    __hip_bfloat16* xbf  = (__hip_bfloat16*)(ws + WS_XBF);     // aliases yo (x dead before win_attn)
    __hip_bfloat16* zbuf = (__hip_bfloat16*)(ws + 12845056);   // aliases qkvw (dead after win_attn);
                                                               // must NOT alias yo (k_dwfuse reads yo while writing z)
    __hip_bfloat16* wqkv = (__hip_bfloat16*)(ws + WS_WQKV);    //   884,736 B
    __hip_bfloat16* wdwx = (__hip_bfloat16*)(ws + WS_WDWX);
    __hip_bfloat16* bdwx = (__hip_bfloat16*)(ws + WS_BDWX);
    __hip_bfloat16* wdw  = (__hip_bfloat16*)(ws + WS_WDW);
    __hip_bfloat16* bdw  = (__hip_bfloat16*)(ws + WS_BDW);
    __hip_bfloat16* wpw  = (__hip_bfloat16*)(ws + WS_WPW);
    __hip_bfloat16* bpw  = (__hip_bfloat16*)(ws + WS_BPW);
    int*            flag = (int*)(ws + 114704128);

    k_detect<<<1, 256, 0, stream>>>((const ushort*)d_in[0], flag);
    // ONE fused launch: 8 dtype-converts + pool (pool reads raw input -> no convert dependency)
    k_cvt_pool<<<14923, 256, 0, stream>>>(d_in[0], d_in[1], d_in[2], d_in[3],
                                          d_in[4], d_in[5], d_in[6], d_in[7],
                                          ws, flag);

    k_gemm_qkv_coarse<<<dim3(36, 64), 256, 0, stream>>>((const ushort*)xc, (const ushort*)wqkv,
                                                        qhp, qlp, khp, klp, vtp);
    // MERGED: coarse attention (256 blocks, resident first) + fine qkv gemm (2304 blocks)
    k_fine_cattn<<<2560, 256, 0, stream>>>((const ushort*)xbf, (const ushort*)wqkv, qkvw,
                                           (const ushort*)qhp, (const ushort*)qlp,
                                           (const ushort*)khp, (const ushort*)klp,
                                           (const ushort*)vtp, idx, xo);
    k_win_attn<<<4096, 256, 0, stream>>>(qkvw, idx, yo);
    k_dwfuse<<<4096, 192, 0, stream>>>(xo, yo, wdwx, bdwx, wdw, bdw, zbuf);
    k_gemm_pw<<<768, 256, 0, stream>>>((const ushort*)zbuf, (const ushort*)wpw, bpw, d_out, flag);
}